// Round 11
// baseline (118.394 us; speedup 1.0000x reference)
//
#include <hip/hip_runtime.h>
#include <hip/hip_bf16.h>

// DifferenceOfGaussians on MI355X — round 11: 3 kernels (hpass, vdet, emit).
// vdog+detect FUSED without grid sync: block = (scale, 16-row stripe) x all
// 512 columns; each block computes the 4 vertical convs (planes s-1..s+2) it
// needs, forms 3 DoG planes in registers, does the 3x3x3 max via LDS, writes
// rowbits + gcnt. The dog[] intermediate is gone. Rationale: rounds 8/10
// proved conv micro-opts are null; per-dispatch overhead (~10us) dominates,
// so cut a dispatch. W=32 window is round-10-proven.
//
// Standing lessons:
//  - Fused grid barriers on gfx950: ~100us/barrier (r5/r6). Do not re-fuse all.
//  - __launch_bounds__ occupancy clamps (r8: (64,3)) corrupt replays. Plain only.
//  - fp64 accumulation is the correctness anchor (absmax 0.0). Keep.
//
// Workspace (bytes):
//   OFF_H    : float h[14][640][512] = 18,350,080 (rows 44..555 data,
//              0..43 & 556..599 zero guards, 600..639 prefetch-only dead)
//   OFF_BITS : u64 rowbits[6656][8]  =    425,984 (scales 1..11 written)
//   OFF_GCNT : int gcnt[832]         (groups 64..767 written)

#define OFF_H    0
#define OFF_BITS 18350080
#define OFF_GCNT 18776064

#define HROWS 640
#define HPAD  44
#define MAXPEAKS 32768

// Normalized weights, zero-padded to 96, one 64-lane wave.
// Matches reference exp(-(d/(2s))^2) / sum.
__device__ __forceinline__ void make_w(float s, double sgn, double* wl, int lane) {
    int r = (int)(4.0f * s + 0.5f);
    int n = 2 * r + 1;
    double v0 = 0.0, v1 = 0.0;
    double sd = (double)s;
    if (lane < n) {
        double d = (double)(lane - r), q = d / (2.0 * sd);
        v0 = exp(-q * q);
    }
    if (lane + 64 < n) {
        double d = (double)(lane + 64 - r), q = d / (2.0 * sd);
        v1 = exp(-q * q);
    }
    double part = v0 + v1;
    for (int m = 1; m < 64; m <<= 1) part += __shfl_xor(part, m);
    double inv = sgn / part;
    wl[lane] = v0 * inv;
    if (lane + 64 < 96) wl[lane + 64] = v1 * inv;
}

// ---- 1: horizontal blur + guard zeroing; 16 outputs/thread ----
// block 256 = 8 rows x 32 threads; grid (64 rowgroups, 14 planes), heavy first
__global__ __launch_bounds__(256) void hpass(const float* __restrict__ x,
                                             const float* __restrict__ sigma_list,
                                             float* __restrict__ h) {
    const int i = 13 - blockIdx.y;        // heavy plane first
    const int t = threadIdx.x;
    float s = sigma_list[i];
    int r = (int)(4.0f * s + 0.5f);
    int n = 2 * r + 1;
    int nceil = (n + 15) & ~15;

    __shared__ double wl[96];
    if (t < 64) make_w(s, +1.0, wl, t);

    // zero this block's share of the 88 guard rows (64 blocks x 704 = 88*512)
    {
        float* hp = h + i * (HROWS * 512);
        for (int k = t; k < 704; k += 256) {
            int f = blockIdx.x * 704 + k;      // 0..45055
            int g = f >> 9, xc = f & 511;      // g in 0..87
            int row = (g < HPAD) ? g : (g + 512);   // 0..43, 556..599
            hp[row * 512 + xc] = 0.0f;
        }
    }

    // stage 8 zero-padded rows, skewed (addr = p + p/16); x-pad stays 43
    __shared__ float rowp[8][648];
    int y8 = blockIdx.x * 8;
    for (int rr = 0; rr < 8; ++rr)
        for (int k = t; k < 608; k += 256) {
            int gx = k - 43;
            float val = ((unsigned)gx < 512u) ? x[(y8 + rr) * 512 + gx] : 0.0f;
            rowp[rr][k + (k >> 4)] = val;
        }
    __syncthreads();

    int tsub = t & 31, row = t >> 5;
    int xb = tsub * 16;
    int P0 = 43 - r + xb;
    double acc[16], win[16];
#pragma unroll
    for (int j = 0; j < 16; ++j) acc[j] = 0.0;
#pragma unroll
    for (int sl = 0; sl < 16; ++sl) {
        int p = P0 + sl;
        win[sl] = (double)rowp[row][p + (p >> 4)];
    }
    for (int dc = 0; dc < nceil; dc += 16) {
#pragma unroll
        for (int k = 0; k < 16; ++k) {
            double wd = wl[dc + k];
#pragma unroll
            for (int j = 0; j < 16; ++j)
                acc[j] = fma(wd, win[(k + j) & 15], acc[j]);
            int p = P0 + dc + k + 16;
            win[k] = (double)rowp[row][p + (p >> 4)];
        }
    }
    float* hp = h + (i * HROWS + HPAD + y8 + row) * 512 + xb;
#pragma unroll
    for (int j = 0; j < 16; ++j) hp[j] = (float)acc[j];
}

// 18-row vertical conv, 32-slot rotating window (round-10-proven pattern).
// bp points at padded row (HPAD + y0 - 1 - r) + col. Taps d=0..nc-1; output
// row j needs input rel-row d+j (j 0..17). Refill slot k <- rel-row dc+32+k
// right after tap k, so tap k' (j up to 17) always finds its row resident.
// Max prefetch rel-row = nc+31 -> padded row <= 623 < 640 (in-bounds dead).
// Real taps (w!=0) reach padded row <= 599 = last zero guard.
__device__ __forceinline__ void conv18(const float* __restrict__ bp,
                                       int nceil, const double* __restrict__ wl,
                                       double (&g)[18]) {
    double win[32];
#pragma unroll
    for (int sl = 0; sl < 32; ++sl) win[sl] = (double)bp[sl * 512];
#pragma unroll
    for (int j = 0; j < 18; ++j) g[j] = 0.0;
    int dc = 0;
    for (; dc + 32 <= nceil; dc += 32) {
        const float* rp = bp + (dc + 32) * 512;
#pragma unroll
        for (int k = 0; k < 32; ++k) {
            double wd = wl[dc + k];
#pragma unroll
            for (int j = 0; j < 18; ++j)
                g[j] = fma(wd, win[(k + j) & 31], g[j]);
            win[k] = (double)rp[k * 512];
        }
    }
    if (nceil & 16) {
        const float* rp = bp + (dc + 32) * 512;
#pragma unroll
        for (int k = 0; k < 16; ++k) {
            double wd = wl[dc + k];
#pragma unroll
            for (int j = 0; j < 18; ++j)
                g[j] = fma(wd, win[(k + j) & 31], g[j]);
            win[k] = (double)rp[k * 512];
        }
    }
}

// ---- 2: fused vertical-DoG + 3x3x3 peak detect ----
// grid (32 y-stripes, 11 scales heavy-first), block 512 (lane = column).
__global__ __launch_bounds__(512) void vdet(const float* __restrict__ h,
                                            const float* __restrict__ sigma_list,
                                            unsigned long long* __restrict__ rowbits,
                                            int* __restrict__ gcnt) {
    const int s = 11 - blockIdx.y;        // 11..1, heavy first
    const int yt = blockIdx.x;            // 0..31
    const int y0 = yt * 16;
    const int t = threadIdx.x;            // column 0..511
    const int wv = t >> 6, lane = t & 63;

    __shared__ double wl[4][96];
    __shared__ float rmAll[512][17];      // +1 pad: conflict-free
    __shared__ int cnt[16][8];

    if (wv < 4) make_w(sigma_list[s - 1 + wv], +1.0, wl[wv], lane);
    __syncthreads();

    int r[4], nc[4];
#pragma unroll
    for (int p = 0; p < 4; ++p) {
        float sp = sigma_list[s - 1 + p];
        r[p] = (int)(4.0f * sp + 0.5f);
        nc[p] = (2 * r[p] + 16) & ~15;    // (n+15)&~15 with n=2r+1
    }
    const int PS = HROWS * 512;
    const float* hb = h + (s - 1) * PS;

    double A[18], B[18];
    float pm3[18], vcen[16];

    conv18(hb + (HPAD + y0 - 1 - r[0]) * 512 + t, nc[0], wl[0], A);   // g_{s-1}
    conv18(hb + PS + (HPAD + y0 - 1 - r[1]) * 512 + t, nc[1], wl[1], B); // g_s
    {
        double sg = (double)sigma_list[s - 1];
#pragma unroll
        for (int j = 0; j < 18; ++j) pm3[j] = (float)((A[j] - B[j]) * sg);
    }
    conv18(hb + 2 * PS + (HPAD + y0 - 1 - r[2]) * 512 + t, nc[2], wl[2], A); // g_{s+1}
    {
        double sg = (double)sigma_list[s];
#pragma unroll
        for (int j = 0; j < 18; ++j) {
            float d = (float)((B[j] - A[j]) * sg);
            pm3[j] = fmaxf(pm3[j], d);
            if (j >= 1 && j <= 16) vcen[j - 1] = d;   // center plane s values
        }
    }
    conv18(hb + 3 * PS + (HPAD + y0 - 1 - r[3]) * 512 + t, nc[3], wl[3], B); // g_{s+2}
    {
        double sg = (double)sigma_list[s + 1];
#pragma unroll
        for (int j = 0; j < 18; ++j)
            pm3[j] = fmaxf(pm3[j], (float)((A[j] - B[j]) * sg));
    }

    // 3-row max of the 3-plane column max; rows y0-1..y0+16 -> k=0..15
#pragma unroll
    for (int k = 0; k < 16; ++k)
        rmAll[t][k] = fmaxf(pm3[k], fmaxf(pm3[k + 1], pm3[k + 2]));
    __syncthreads();

#pragma unroll
    for (int k = 0; k < 16; ++k) {
        int y = y0 + k;
        bool peak = false;
        if (t >= 1 && t <= 510 && y >= 1 && y <= 510) {
            float v = vcen[k];
            if (v > 0.001f) {
                float mx = fmaxf(rmAll[t - 1][k],
                           fmaxf(rmAll[t][k], rmAll[t + 1][k]));
                peak = (v >= mx);          // mx includes v
            }
        }
        unsigned long long m = __ballot(peak);
        if (lane == 0) {
            rowbits[(s * 512 + y) * 8 + wv] = m;
            cnt[k][wv] = __popcll(m);
        }
    }
    __syncthreads();
    if (t < 2) {                           // two 8-row groups per block
        int c = 0;
#pragma unroll
        for (int k = 0; k < 8; ++k)
#pragma unroll
            for (int q = 0; q < 8; ++q) c += cnt[t * 8 + k][q];
        gcnt[s * 64 + yt * 2 + t] = c;
    }
}

// ---- 3: ordered emit + padding fill; per-block redundant group reduce ----
// grid 832 blocks x 512 (block b covers scale b/64, rows (b%64)*8 .. +7).
// Border groups (s=0,12) never written: synthesize zeros, guard all reads.
__global__ __launch_bounds__(512) void emit(const unsigned long long* __restrict__ rowbits,
                                            const int* __restrict__ gcnt,
                                            const float* __restrict__ sigma_list,
                                            float* __restrict__ out) {
    const int b = blockIdx.x;
    const int s = b >> 6;
    const int y0 = (b & 63) * 8;
    const int t = threadIdx.x;
    const int lane = t & 63;
    const bool interior = (s >= 1 && s <= 11);

    __shared__ unsigned long long m[64];   // [row k][word q]
    __shared__ int pre[64];                // exclusive word prefix (row-major)
    __shared__ int redA[512], redB[512];

    if (interior && t < 64)
        m[t] = rowbits[(s * 512 + y0 + (t >> 3)) * 8 + (t & 7)];

    int pa = 0, pb = 0;
    {
        int c0 = (t >= 64) ? gcnt[t] : 0;            // groups 0..63 border
        int i1 = t + 512;
        int c1 = (i1 < 768) ? gcnt[i1] : 0;          // 768..831 border
        pb = c0 + c1;
        if (t < b) pa += c0;
        if (i1 < b) pa += c1;
    }
    redA[t] = pa;
    redB[t] = pb;
    __syncthreads();
    for (int off = 256; off > 0; off >>= 1) {
        if (t < off) { redA[t] += redA[t + off]; redB[t] += redB[t + off]; }
        __syncthreads();
    }
    int gbase = redA[0];
    int tot = min(redB[0], MAXPEAKS);

    if (interior) {
        if (t < 64) {                      // wave-0 exclusive scan of word counts
            int wc = (int)__popcll(m[t]);
            int inc = wc;
            for (int off = 1; off < 64; off <<= 1) {
                int v = __shfl_up(inc, off);
                if (lane >= off) inc += v;
            }
            pre[t] = inc - wc;
        }
        __syncthreads();

#pragma unroll
        for (int k = 0; k < 8; ++k) {
            int widx = k * 8 + (t >> 6);
            unsigned long long mw = m[widx];
            if ((mw >> lane) & 1ull) {
                int pos = gbase + pre[widx] + (int)__popcll(mw & ((1ull << lane) - 1ull));
                if (pos < MAXPEAKS) {
                    out[pos * 3 + 0] = sigma_list[s];
                    out[pos * 3 + 1] = (float)(y0 + k);
                    out[pos * 3 + 2] = (float)t;
                }
            }
        }
    }

    int idx = b * 512 + t;                 // blocks 0..63 cover all 32768 rows
    if (idx < MAXPEAKS && idx >= tot) {
        out[idx * 3 + 0] = sigma_list[0];
        out[idx * 3 + 1] = 0.0f;
        out[idx * 3 + 2] = 0.0f;
    }
}

extern "C" void kernel_launch(void* const* d_in, const int* in_sizes, int n_in,
                              void* d_out, int out_size, void* d_ws, size_t ws_size,
                              hipStream_t stream) {
    const float* x     = (const float*)d_in[0];   // [1,1,512,512]
    const float* sigma = (const float*)d_in[2];   // [14]
    float* out = (float*)d_out;                   // [32768,3]

    char* ws = (char*)d_ws;
    float* h                     = (float*)(ws + OFF_H);
    unsigned long long* rowbits  = (unsigned long long*)(ws + OFF_BITS);
    int* gcnt                    = (int*)(ws + OFF_GCNT);

    hpass<<<dim3(64, 14), 256, 0, stream>>>(x, sigma, h);
    vdet<<<dim3(32, 11), 512, 0, stream>>>(h, sigma, rowbits, gcnt);
    emit<<<832, 512, 0, stream>>>(rowbits, gcnt, sigma, out);
}